// Round 1
// baseline (144.059 us; speedup 1.0000x reference)
//
#include <hip/hip_runtime.h>
#include <hip/hip_bf16.h>
#include <math.h>

#define DD 1024
#define MM 8192

typedef __attribute__((ext_vector_type(8))) short short8;
typedef __attribute__((ext_vector_type(4))) float f32x4;

__device__ inline unsigned short f32_to_bf16(float f) {
  union { float f; unsigned u; } v; v.f = f;
  unsigned u = v.u;
  u += 0x7FFFu + ((u >> 16) & 1u);   // round-to-nearest-even
  return (unsigned short)(u >> 16);
}

__global__ void k_convert_x(const float4* __restrict__ x, ushort4* __restrict__ o, int n4) {
  int i = blockIdx.x * blockDim.x + threadIdx.x;
  int stride = gridDim.x * blockDim.x;
  for (; i < n4; i += stride) {
    float4 v = x[i];
    ushort4 r;
    r.x = f32_to_bf16(v.x); r.y = f32_to_bf16(v.y);
    r.z = f32_to_bf16(v.z); r.w = f32_to_bf16(v.w);
    o[i] = r;
  }
}

// 32x32 LDS-tiled transpose, f32 in -> bf16 out. W is (K=D, N=D) row-major;
// output is W^T (N, K) row-major so GEMM B-fragments are contiguous-K.
__global__ void k_transpose_w(const float* __restrict__ w0, const float* __restrict__ w1,
                              const float* __restrict__ w2, const float* __restrict__ w3,
                              unsigned short* __restrict__ o0, unsigned short* __restrict__ o1,
                              unsigned short* __restrict__ o2, unsigned short* __restrict__ o3) {
  const float* src; unsigned short* dst;
  switch (blockIdx.z) {
    case 0: src = w0; dst = o0; break;
    case 1: src = w1; dst = o1; break;
    case 2: src = w2; dst = o2; break;
    default: src = w3; dst = o3; break;
  }
  __shared__ float t[32][33];
  int tx = threadIdx.x, ty = threadIdx.y;          // 32 x 8
  int c0 = blockIdx.x * 32, r0 = blockIdx.y * 32;
  #pragma unroll
  for (int i = 0; i < 4; i++)
    t[ty + 8 * i][tx] = src[(size_t)(r0 + ty + 8 * i) * DD + c0 + tx];
  __syncthreads();
  #pragma unroll
  for (int i = 0; i < 4; i++)
    dst[(size_t)(c0 + ty + 8 * i) * DD + r0 + tx] = f32_to_bf16(t[tx][ty + 8 * i]);
}

__global__ void k_scale(const float* __restrict__ vqc, float* __restrict__ sc) {
  int d = blockIdx.x * blockDim.x + threadIdx.x;
  if (d < DD) {
    float th = vqc[d * 4 + 0] * 0.5f, ph = vqc[d * 4 + 1];
    sc[d] = cosf(th) + sinf(th) * cosf(ph);
  }
}

// C[M,N] = act(A[M,K] @ B + bias); B given as B^T (N,K) row-major bf16.
// EPI: 0=tanh->bf16, 1=(z+b)*scale[n]->bf16, 2=silu->bf16, 3=identity->f32
template <int EPI>
__global__ void k_gemm(const unsigned short* __restrict__ A,
                       const unsigned short* __restrict__ Bt,
                       const float* __restrict__ bias,
                       const float* __restrict__ scale,
                       void* __restrict__ Cout) {
  constexpr int K = DD, N = DD;
  __shared__ unsigned short As[128 * 32];   // 8 KB, [row][k] linear (global_load_lds needs linear)
  __shared__ unsigned short Bs[128 * 32];   // 8 KB, [n][k]
  const int tid = threadIdx.x;
  const int wave = tid >> 6, lane = tid & 63;
  const int wr = wave >> 1, wc = wave & 1;          // 2x2 waves over 128x128 tile
  const int rowA0 = blockIdx.y * 128, colB0 = blockIdx.x * 128;
  const int lr = lane & 15, lk = (lane >> 4) * 8;   // MFMA fragment addressing
  const int seg = wave * 2;                          // two 16-row segments per wave
  const int srow = lane >> 2;                        // staging: row within segment
  const int skc = (lane & 3) * 8;                    // staging: k offset (8 bf16 = 16B)

  f32x4 acc[4][4] = {};

  for (int k0 = 0; k0 < K; k0 += 32) {
    #pragma unroll
    for (int i = 0; i < 2; i++) {
      int s = seg + i;
      const unsigned short* ga = A + (size_t)(rowA0 + s * 16 + srow) * K + k0 + skc;
      __builtin_amdgcn_global_load_lds(
          (const __attribute__((address_space(1))) unsigned int*)ga,
          (__attribute__((address_space(3))) unsigned int*)(As + s * 512), 16, 0, 0);
      const unsigned short* gb = Bt + (size_t)(colB0 + s * 16 + srow) * K + k0 + skc;
      __builtin_amdgcn_global_load_lds(
          (const __attribute__((address_space(1))) unsigned int*)gb,
          (__attribute__((address_space(3))) unsigned int*)(Bs + s * 512), 16, 0, 0);
    }
    __syncthreads();   // compiler drains vmcnt before s_barrier

    short8 a[4], b[4];
    #pragma unroll
    for (int m = 0; m < 4; m++)
      a[m] = *(const short8*)(As + (wr * 64 + m * 16 + lr) * 32 + lk);
    #pragma unroll
    for (int n = 0; n < 4; n++)
      b[n] = *(const short8*)(Bs + (wc * 64 + n * 16 + lr) * 32 + lk);
    #pragma unroll
    for (int m = 0; m < 4; m++)
      #pragma unroll
      for (int n = 0; n < 4; n++)
        acc[m][n] = __builtin_amdgcn_mfma_f32_16x16x32_bf16(a[m], b[n], acc[m][n], 0, 0, 0);
    __syncthreads();
  }

  // Epilogue. C/D layout: col = lane&15, row = (lane>>4)*4 + j  [m89/m91 verified]
  const int row0 = rowA0 + wr * 64;
  const int col0 = colB0 + wc * 64;
  #pragma unroll
  for (int n = 0; n < 4; n++) {
    const int col = col0 + n * 16 + lr;
    const float bv = bias[col];
    const float sv = (EPI == 1) ? scale[col] : 0.f;
    #pragma unroll
    for (int m = 0; m < 4; m++) {
      #pragma unroll
      for (int j = 0; j < 4; j++) {
        int row = row0 + m * 16 + (lane >> 4) * 4 + j;
        float z = acc[m][n][j] + bv;
        if constexpr (EPI == 0) {
          ((unsigned short*)Cout)[(size_t)row * N + col] = f32_to_bf16(tanhf(z));
        } else if constexpr (EPI == 1) {
          ((unsigned short*)Cout)[(size_t)row * N + col] = f32_to_bf16(z * sv);
        } else if constexpr (EPI == 2) {
          ((unsigned short*)Cout)[(size_t)row * N + col] = f32_to_bf16(z / (1.f + __expf(-z)));
        } else {
          ((float*)Cout)[(size_t)row * N + col] = z;
        }
      }
    }
  }
}

extern "C" void kernel_launch(void* const* d_in, const int* in_sizes, int n_in,
                              void* d_out, int out_size, void* d_ws, size_t ws_size,
                              hipStream_t stream) {
  const float* x   = (const float*)d_in[0];
  const float* W1  = (const float*)d_in[1];
  const float* b1  = (const float*)d_in[2];
  const float* W2  = (const float*)d_in[3];
  const float* b2  = (const float*)d_in[4];
  const float* vqc = (const float*)d_in[5];
  const float* Wp1 = (const float*)d_in[6];
  const float* bp1 = (const float*)d_in[7];
  const float* Wp2 = (const float*)d_in[8];
  const float* bp2 = (const float*)d_in[9];

  char* ws = (char*)d_ws;
  unsigned short* actA = (unsigned short*)ws;                    // 16 MB: xb, then gemm2 out
  unsigned short* actB = (unsigned short*)(ws + (16u << 20));    // 16 MB: gemm1/gemm3 out
  unsigned short* Wt0  = (unsigned short*)(ws + (32u << 20));    // 2 MB each
  unsigned short* Wt1  = (unsigned short*)(ws + (34u << 20));
  unsigned short* Wt2  = (unsigned short*)(ws + (36u << 20));
  unsigned short* Wt3  = (unsigned short*)(ws + (38u << 20));
  float* scale = (float*)(ws + (40u << 20));                     // 4 KB

  k_convert_x<<<2048, 256, 0, stream>>>((const float4*)x, (ushort4*)actA, MM * DD / 4);
  k_transpose_w<<<dim3(32, 32, 4), dim3(32, 8), 0, stream>>>(W1, W2, Wp1, Wp2, Wt0, Wt1, Wt2, Wt3);
  k_scale<<<4, 256, 0, stream>>>(vqc, scale);

  dim3 g(DD / 128, MM / 128), b(256);
  k_gemm<0><<<g, b, 0, stream>>>(actA, Wt0, b1,  nullptr, actB);   // tanh(x@W1+b1)
  k_gemm<1><<<g, b, 0, stream>>>(actB, Wt1, b2,  scale,   actA);   // (·@W2+b2)*scale
  k_gemm<2><<<g, b, 0, stream>>>(actA, Wt2, bp1, nullptr, actB);   // silu(q@Wp1+bp1)
  k_gemm<3><<<g, b, 0, stream>>>(actB, Wt3, bp2, nullptr, d_out);  // ·@Wp2+bp2 -> f32
}

// Round 2
// 118.758 us; speedup vs baseline: 1.2130x; 1.2130x over previous
//
#include <hip/hip_runtime.h>
#include <hip/hip_bf16.h>
#include <math.h>

#define DD 1024
#define MM 8192

typedef __attribute__((ext_vector_type(8))) short short8;
typedef __attribute__((ext_vector_type(4))) float f32x4;

__device__ inline unsigned short f32_to_bf16(float f) {
  union { float f; unsigned u; } v; v.f = f;
  unsigned u = v.u;
  u += 0x7FFFu + ((u >> 16) & 1u);   // round-to-nearest-even
  return (unsigned short)(u >> 16);
}

__global__ void k_convert_x(const float4* __restrict__ x, ushort4* __restrict__ o, int n4) {
  int i = blockIdx.x * blockDim.x + threadIdx.x;
  int stride = gridDim.x * blockDim.x;
  for (; i < n4; i += stride) {
    float4 v = x[i];
    ushort4 r;
    r.x = f32_to_bf16(v.x); r.y = f32_to_bf16(v.y);
    r.z = f32_to_bf16(v.z); r.w = f32_to_bf16(v.w);
    o[i] = r;
  }
}

// 32x32 LDS-tiled transpose, f32 in -> bf16 out. W is (K=D, N=D) row-major;
// output is W^T (N, K) row-major so GEMM B-fragments are contiguous-K.
__global__ void k_transpose_w(const float* __restrict__ w0, const float* __restrict__ w1,
                              const float* __restrict__ w2, const float* __restrict__ w3,
                              unsigned short* __restrict__ o0, unsigned short* __restrict__ o1,
                              unsigned short* __restrict__ o2, unsigned short* __restrict__ o3) {
  const float* src; unsigned short* dst;
  switch (blockIdx.z) {
    case 0: src = w0; dst = o0; break;
    case 1: src = w1; dst = o1; break;
    case 2: src = w2; dst = o2; break;
    default: src = w3; dst = o3; break;
  }
  __shared__ float t[32][33];
  int tx = threadIdx.x, ty = threadIdx.y;          // 32 x 8
  int c0 = blockIdx.x * 32, r0 = blockIdx.y * 32;
  #pragma unroll
  for (int i = 0; i < 4; i++)
    t[ty + 8 * i][tx] = src[(size_t)(r0 + ty + 8 * i) * DD + c0 + tx];
  __syncthreads();
  #pragma unroll
  for (int i = 0; i < 4; i++)
    dst[(size_t)(c0 + ty + 8 * i) * DD + r0 + tx] = f32_to_bf16(t[tx][ty + 8 * i]);
}

__global__ void k_scale(const float* __restrict__ vqc, float* __restrict__ sc) {
  int d = blockIdx.x * blockDim.x + threadIdx.x;
  if (d < DD) {
    float th = vqc[d * 4 + 0] * 0.5f, ph = vqc[d * 4 + 1];
    sc[d] = cosf(th) + sinf(th) * cosf(ph);
  }
}

// C[M,N] = act(A[M,K] @ B + bias); B given as B^T (N,K) row-major bf16.
// BK=64, LDS XOR-swizzled (slot ^= row&7 on BOTH source-preswizzle and read),
// XCD-bijective block swizzle so the 8 blocks sharing an A-row-panel land on
// one XCD's L2.
// EPI: 0=tanh->bf16, 1=(z+b)*scale[n]->bf16, 2=silu->bf16, 3=identity->f32
template <int EPI>
__global__ void k_gemm(const unsigned short* __restrict__ A,
                       const unsigned short* __restrict__ Bt,
                       const float* __restrict__ bias,
                       const float* __restrict__ scale,
                       void* __restrict__ Cout) {
  constexpr int K = DD, N = DD;
  __shared__ unsigned short As[128 * 64];   // 16 KB, [row][k] linear dest
  __shared__ unsigned short Bs[128 * 64];   // 16 KB, [n][k]
  const int tid = threadIdx.x;
  const int wave = tid >> 6, lane = tid & 63;
  const int wr = wave >> 1, wc = wave & 1;          // 2x2 waves over 128x128 tile

  // XCD swizzle: bit-permutation of the 512-block linear id. Same-by (same
  // A-panel) blocks get ids congruent mod 8 -> same XCD.
  const int L = blockIdx.y * gridDim.x + blockIdx.x;
  const int bx = (L >> 3) & 7;
  const int by = (L & 7) | ((L >> 6) << 3);
  const int rowA0 = by * 128, colB0 = bx * 128;

  const int lr = lane & 15, lk = (lane >> 4) * 8;   // MFMA fragment addressing
  const int srow = lane >> 3;                        // staging: row within 8-row segment
  const int sswz = ((lane & 7) ^ srow) * 8;          // pre-swizzled k-slot (shorts)

  f32x4 acc[4][4] = {};

  for (int k0 = 0; k0 < K; k0 += 64) {
    #pragma unroll
    for (int i = 0; i < 4; i++) {
      int r = wave * 32 + i * 8;                     // wave-uniform segment base
      const unsigned short* ga = A + (size_t)(rowA0 + r + srow) * K + k0 + sswz;
      __builtin_amdgcn_global_load_lds(
          (const __attribute__((address_space(1))) unsigned int*)ga,
          (__attribute__((address_space(3))) unsigned int*)(As + r * 64), 16, 0, 0);
      const unsigned short* gb = Bt + (size_t)(colB0 + r + srow) * K + k0 + sswz;
      __builtin_amdgcn_global_load_lds(
          (const __attribute__((address_space(1))) unsigned int*)gb,
          (__attribute__((address_space(3))) unsigned int*)(Bs + r * 64), 16, 0, 0);
    }
    __syncthreads();   // compiler drains vmcnt before s_barrier

    #pragma unroll
    for (int kk = 0; kk < 64; kk += 32) {
      short8 a[4], b[4];
      #pragma unroll
      for (int m = 0; m < 4; m++) {
        int row = wr * 64 + m * 16 + lr;
        a[m] = *(const short8*)(As + row * 64 + (((((kk + lk) >> 3)) ^ (row & 7)) << 3));
      }
      #pragma unroll
      for (int n = 0; n < 4; n++) {
        int row = wc * 64 + n * 16 + lr;
        b[n] = *(const short8*)(Bs + row * 64 + (((((kk + lk) >> 3)) ^ (row & 7)) << 3));
      }
      #pragma unroll
      for (int m = 0; m < 4; m++)
        #pragma unroll
        for (int n = 0; n < 4; n++)
          acc[m][n] = __builtin_amdgcn_mfma_f32_16x16x32_bf16(a[m], b[n], acc[m][n], 0, 0, 0);
    }
    __syncthreads();
  }

  // Epilogue. C/D layout: col = lane&15, row = (lane>>4)*4 + j  [m89/m91 verified]
  const int row0 = rowA0 + wr * 64;
  const int col0 = colB0 + wc * 64;
  #pragma unroll
  for (int n = 0; n < 4; n++) {
    const int col = col0 + n * 16 + lr;
    const float bv = bias[col];
    const float sv = (EPI == 1) ? scale[col] : 0.f;
    #pragma unroll
    for (int m = 0; m < 4; m++) {
      #pragma unroll
      for (int j = 0; j < 4; j++) {
        int row = row0 + m * 16 + (lane >> 4) * 4 + j;
        float z = acc[m][n][j] + bv;
        if constexpr (EPI == 0) {
          ((unsigned short*)Cout)[(size_t)row * N + col] = f32_to_bf16(tanhf(z));
        } else if constexpr (EPI == 1) {
          ((unsigned short*)Cout)[(size_t)row * N + col] = f32_to_bf16(z * sv);
        } else if constexpr (EPI == 2) {
          ((unsigned short*)Cout)[(size_t)row * N + col] = f32_to_bf16(z / (1.f + __expf(-z)));
        } else {
          ((float*)Cout)[(size_t)row * N + col] = z;
        }
      }
    }
  }
}

extern "C" void kernel_launch(void* const* d_in, const int* in_sizes, int n_in,
                              void* d_out, int out_size, void* d_ws, size_t ws_size,
                              hipStream_t stream) {
  const float* x   = (const float*)d_in[0];
  const float* W1  = (const float*)d_in[1];
  const float* b1  = (const float*)d_in[2];
  const float* W2  = (const float*)d_in[3];
  const float* b2  = (const float*)d_in[4];
  const float* vqc = (const float*)d_in[5];
  const float* Wp1 = (const float*)d_in[6];
  const float* bp1 = (const float*)d_in[7];
  const float* Wp2 = (const float*)d_in[8];
  const float* bp2 = (const float*)d_in[9];

  char* ws = (char*)d_ws;
  unsigned short* actA = (unsigned short*)ws;                    // 16 MB: xb, then gemm2 out
  unsigned short* actB = (unsigned short*)(ws + (16u << 20));    // 16 MB: gemm1/gemm3 out
  unsigned short* Wt0  = (unsigned short*)(ws + (32u << 20));    // 2 MB each
  unsigned short* Wt1  = (unsigned short*)(ws + (34u << 20));
  unsigned short* Wt2  = (unsigned short*)(ws + (36u << 20));
  unsigned short* Wt3  = (unsigned short*)(ws + (38u << 20));
  float* scale = (float*)(ws + (40u << 20));                     // 4 KB

  k_convert_x<<<2048, 256, 0, stream>>>((const float4*)x, (ushort4*)actA, MM * DD / 4);
  k_transpose_w<<<dim3(32, 32, 4), dim3(32, 8), 0, stream>>>(W1, W2, Wp1, Wp2, Wt0, Wt1, Wt2, Wt3);
  k_scale<<<4, 256, 0, stream>>>(vqc, scale);

  dim3 g(DD / 128, MM / 128), b(256);
  k_gemm<0><<<g, b, 0, stream>>>(actA, Wt0, b1,  nullptr, actB);   // tanh(x@W1+b1)
  k_gemm<1><<<g, b, 0, stream>>>(actB, Wt1, b2,  scale,   actA);   // (·@W2+b2)*scale
  k_gemm<2><<<g, b, 0, stream>>>(actA, Wt2, bp1, nullptr, actB);   // silu(q@Wp1+bp1)
  k_gemm<3><<<g, b, 0, stream>>>(actB, Wt3, bp2, nullptr, d_out);  // ·@Wp2+bp2 -> f32
}